// Round 3
// baseline (557.750 us; speedup 1.0000x reference)
//
#include <hip/hip_runtime.h>
#include <hip/hip_bf16.h>

typedef __bf16 bf16_t;
typedef bf16_t bf16x8 __attribute__((ext_vector_type(8)));
typedef float f32x4 __attribute__((ext_vector_type(4)));

constexpr int D_DIM = 1024;
constexpr int S_DIM = 4096;
constexpr int B_DIM = 4;

// ---------------- elementwise cast X: fp32 -> bf16 ----------------
__global__ void cast_f32_bf16(const float* __restrict__ in, bf16_t* __restrict__ out) {
  size_t i = ((size_t)blockIdx.x * blockDim.x + threadIdx.x) * 8;
  float4 a = *(const float4*)(in + i);
  float4 b = *(const float4*)(in + i + 4);
  bf16x8 o;
  o[0] = (bf16_t)a.x; o[1] = (bf16_t)a.y; o[2] = (bf16_t)a.z; o[3] = (bf16_t)a.w;
  o[4] = (bf16_t)b.x; o[5] = (bf16_t)b.y; o[6] = (bf16_t)b.z; o[7] = (bf16_t)b.w;
  *(bf16x8*)(out + i) = o;
}

// ---------------- transpose + cast weight: [1024][1024] f32 -> bf16 transposed ----
__global__ void transpose_cast_1024(const float* __restrict__ in, bf16_t* __restrict__ out) {
  __shared__ float t[32][33];
  int x0 = blockIdx.x * 32, y0 = blockIdx.y * 32;
#pragma unroll
  for (int i = 0; i < 32; i += 8)
    t[threadIdx.y + i][threadIdx.x] =
        in[(size_t)(y0 + threadIdx.y + i) * D_DIM + (x0 + threadIdx.x)];
  __syncthreads();
#pragma unroll
  for (int i = 0; i < 32; i += 8)
    out[(size_t)(x0 + threadIdx.y + i) * D_DIM + (y0 + threadIdx.x)] =
        (bf16_t)t[threadIdx.x][threadIdx.y + i];
}

// ================= 256x256 8-phase GEMM (T1..T5 combo) =================
// BM=BN=256, BK=64 per K-tile, 512 threads = 8 waves (2M x 4N), per-wave out 128x64.
// LDS 128 KiB STATIC: buf0{A,B} + buf1{A,B}, each tile 256x64 bf16 = 32 KB.
// Swizzle: physical 16B-granule g of row r holds logical granule g^(r&7)
// (applied on global SOURCE addr for global_load_lds + on ds_read addr; rule #21).
constexpr int BM2 = 256, BN2 = 256;

#define VMCNT4 asm volatile("s_waitcnt vmcnt(4)" ::: "memory")
#define VMCNT0 asm volatile("s_waitcnt vmcnt(0)" ::: "memory")
#define CFENCE asm volatile("" ::: "memory")
#define BAR __builtin_amdgcn_s_barrier()
#define PRIO1 __builtin_amdgcn_s_setprio(1)
#define PRIO0 __builtin_amdgcn_s_setprio(0)

// stage one 128-row x 64-col bf16 half-tile into LDS (2 x global_load_lds, 16B/lane).
// LDS dest is linear (wave-uniform base + lane*16); source granule pre-swizzled.
__device__ __forceinline__ void stage_half(const bf16_t* __restrict__ g, int ld,
                                           char* lds, int tid) {
  const int w = tid >> 6, l = tid & 63;
  const int rw = l >> 3;          // row within this wave's 8-row group (== row&7)
  const int gl = (l & 7) ^ rw;    // swizzled source 16B-granule
  char* l0 = lds + w * 1024;      // wave-uniform
  const bf16_t* s0 = g + (size_t)(w * 8 + rw) * ld + gl * 8;
  __builtin_amdgcn_global_load_lds((const __attribute__((address_space(1))) void*)s0,
                                   (__attribute__((address_space(3))) void*)l0, 16, 0, 0);
  __builtin_amdgcn_global_load_lds(
      (const __attribute__((address_space(1))) void*)(s0 + (size_t)64 * ld),
      (__attribute__((address_space(3))) void*)(l0 + 8192), 16, 0, 0);
}

// load 4 A-frags (M-set s: rows wr + s*64 .. +63) x 2 K-halves, swizzled ds_read_b128
__device__ __forceinline__ void load_a4(const char* __restrict__ At, int wr, int fm, int s,
                                        int kxa, int kxb, bf16x8 (&af)[4][2]) {
#pragma unroll
  for (int m = 0; m < 4; ++m) {
    const char* p = At + (wr + (s * 4 + m) * 16 + fm) * 128;
    af[m][0] = *(const bf16x8*)(p + kxa);
    af[m][1] = *(const bf16x8*)(p + kxb);
  }
}

// load all 4 B-frags (wave's 64-col stripe) x 2 K-halves
__device__ __forceinline__ void load_b8(const char* __restrict__ Bt_, int wc, int fm,
                                        int kxa, int kxb, bf16x8 (&bfr)[4][2]) {
#pragma unroll
  for (int n = 0; n < 4; ++n) {
    const char* p = Bt_ + (wc + n * 16 + fm) * 128;
    bfr[n][0] = *(const bf16x8*)(p + kxa);
    bfr[n][1] = *(const bf16x8*)(p + kxb);
  }
}

// one C-quadrant (4M x 2N frags) x K=64 -> 16 MFMA.
// kh-OUTER order: 8 independent MFMAs between dependent accumulations into the
// same acc[][] (kh-inner emitted dependent pairs back-to-back -> pipe stalls).
__device__ __forceinline__ void mfma_q(f32x4 (&acc)[8][4], const bf16x8 (&af)[4][2],
                                       const bf16x8 (&bfr)[4][2], int ms, int ns) {
#pragma unroll
  for (int kh = 0; kh < 2; ++kh)
#pragma unroll
    for (int m = 0; m < 4; ++m)
#pragma unroll
      for (int n = 0; n < 2; ++n)
        acc[ms * 4 + m][ns * 2 + n] = __builtin_amdgcn_mfma_f32_16x16x32_bf16(
            af[m][kh], bfr[ns * 2 + n][kh], acc[ms * 4 + m][ns * 2 + n], 0, 0, 0);
}

// EPI: 0 = fused QKV projection (Q,K row-major + bias; V transposed + bias)
//      2 = bf16 out, sigmoid(v*scale)   (scores -> P)
//      3 = fp32 out                      (PV -> out)
template <int EPI, bool SWAP>
__global__ __launch_bounds__(512, 2) void gemm256(
    const bf16_t* __restrict__ A, const bf16_t* __restrict__ Bt,
    void* __restrict__ C0, void* __restrict__ C1, void* __restrict__ C2,
    const float* __restrict__ b0, const float* __restrict__ b1, const float* __restrict__ b2,
    int K, int lda, int ldb, int ldc, float scale,
    size_t sA, size_t sB, size_t sC) {
  __shared__ __align__(16) char smem[131072];  // static: avoids dynamic-LDS opt-in path
  char* const A0t = smem;            // buf0 A tile
  char* const B0t = smem + 32768;    // buf0 B tile
  char* const A1t = smem + 65536;    // buf1 A tile
  char* const B1t = smem + 98304;    // buf1 B tile

  const int tid = threadIdx.x;
  const int lane = tid & 63;
  const int w = tid >> 6;
  const int wr = (w >> 2) * 128;     // wave row base (2 M-waves)
  const int wc = (w & 3) * 64;       // wave col base (4 N-waves)
  const int fm = lane & 15;
  const int ssw = (fm & 7) << 4;             // row-dependent swizzle term
  const int kp = (lane >> 4) << 4;           // 0,16,32,48
  const int kxa = kp ^ ssw;                  // physical within-row byte, K-half 0
  const int kxb = (64 | kp) ^ ssw;           // K-half 1

  // ---- T1: bijective XCD-aware block remap (all grids have nwg % 8 == 0).
  // HW assigns XCD = dispatch_id % 8; remap so each XCD owns a contiguous
  // logical chunk -> neighboring tiles share L2-resident panels.
  const int nx = gridDim.x, ny = gridDim.y;
  const int nwg = nx * ny * gridDim.z;
  const int flat = blockIdx.x + nx * (blockIdx.y + ny * blockIdx.z);
  const int q = nwg >> 3;
  const int L = (flat & 7) * q + (flat >> 3);
  const int lx = L % nx;
  const int lt = L / nx;
  const int ly = lt % ny;
  const int lz = lt / ny;

  const int bx = SWAP ? ly : lx;
  const int by = SWAP ? lx : ly;

  const bf16_t* Ag = A + (size_t)lz * sA + (size_t)by * BM2 * lda;
  const bf16_t* Bg = Bt + (size_t)lz * sB + (size_t)bx * BN2 * ldb;

  f32x4 acc[8][4] = {};
  bf16x8 af[4][2], bfr[4][2];

  const int NI = K / 128;  // iterations; each covers 2 K-tiles of 64

  // prologue: tile0 full (buf0) + tile1 B-halves (buf1); tile1 A-halves staged in ph1/ph2.
  stage_half(Ag, lda, A0t, tid);
  stage_half(Ag + (size_t)128 * lda, lda, A0t + 16384, tid);
  stage_half(Bg, ldb, B0t, tid);
  stage_half(Bg + (size_t)128 * ldb, ldb, B0t + 16384, tid);
  stage_half(Bg + 64, ldb, B1t, tid);
  stage_half(Bg + 64 + (size_t)128 * ldb, ldb, B1t + 16384, tid);
  VMCNT4;  // tile0 resident; tile1's 2 B-halves (4 loads) stay in flight
  BAR;

  for (int it = 0; it < NI; ++it) {
    const bool last = (it == NI - 1);
    const bf16_t* Ao  = Ag + (size_t)(2 * it + 1) * 64;  // odd tile (buf1)
    const bf16_t* Ae2 = Ag + (size_t)(2 * it + 2) * 64;  // tile t+2 (buf0)
    const bf16_t* Be2 = Bg + (size_t)(2 * it + 2) * 64;
    const bf16_t* Bo2 = Bg + (size_t)(2 * it + 3) * 64;  // tile t+3 (buf1)

    // ph1: even quad a (M0-3,N0-1); 16 ds_reads; stage A-half0(odd)->buf1
    load_a4(A0t, wr, fm, 0, kxa, kxb, af);
    load_b8(B0t, wc, fm, kxa, kxb, bfr);
    stage_half(Ao, lda, A1t, tid);
    CFENCE; BAR;
    PRIO1; mfma_q(acc, af, bfr, 0, 0); PRIO0;
    BAR;

    // ph2: even quad b (M4-7,N0-1); stage A-half1(odd)->buf1, B-half0(t+2)->buf0
    load_a4(A0t, wr, fm, 1, kxa, kxb, af);
    stage_half(Ao + (size_t)128 * lda, lda, A1t + 16384, tid);
    if (!last) stage_half(Be2, ldb, B0t, tid);
    CFENCE; BAR;
    PRIO1; mfma_q(acc, af, bfr, 1, 0); PRIO0;
    BAR;

    // ph3: even quad c (M4-7,N2-3); stage B-half1(t+2)->buf0
    if (!last) stage_half(Be2 + (size_t)128 * ldb, ldb, B0t + 16384, tid);
    CFENCE; BAR;
    PRIO1; mfma_q(acc, af, bfr, 1, 1); PRIO0;
    BAR;

    // ph4: even quad d (M0-3,N2-3; A reload); counted wait for odd tile
    load_a4(A0t, wr, fm, 0, kxa, kxb, af);
    CFENCE; BAR;
    PRIO1; mfma_q(acc, af, bfr, 0, 1); PRIO0;
    if (last) { VMCNT0; } else { VMCNT4; }  // drains odd tile; leaves B(t+2) in flight
    BAR;

    // ph5: odd quad a; 16 ds_reads from buf1; stage A-half0(t+2)->buf0
    load_a4(A1t, wr, fm, 0, kxa, kxb, af);
    load_b8(B1t, wc, fm, kxa, kxb, bfr);
    if (!last) stage_half(Ae2, lda, A0t, tid);
    CFENCE; BAR;
    PRIO1; mfma_q(acc, af, bfr, 0, 0); PRIO0;
    BAR;

    // ph6: odd quad b; stage A-half1(t+2)->buf0
    load_a4(A1t, wr, fm, 1, kxa, kxb, af);
    if (!last) stage_half(Ae2 + (size_t)128 * lda, lda, A0t + 16384, tid);
    CFENCE; BAR;
    PRIO1; mfma_q(acc, af, bfr, 1, 0); PRIO0;
    BAR;

    // ph7: odd quad c; stage B-half0(t+3)->buf1
    if (!last) stage_half(Bo2, ldb, B1t, tid);
    CFENCE; BAR;
    PRIO1; mfma_q(acc, af, bfr, 1, 1); PRIO0;
    BAR;

    // ph8: odd quad d (A reload); stage B-half1(t+3)->buf1; counted wait for tile t+2
    load_a4(A1t, wr, fm, 0, kxa, kxb, af);
    if (!last) stage_half(Bo2 + (size_t)128 * ldb, ldb, B1t + 16384, tid);
    CFENCE; BAR;
    PRIO1; mfma_q(acc, af, bfr, 0, 1); PRIO0;
    if (!last) { VMCNT4; }  // drains tile t+2; leaves B(t+3) in flight
    BAR;
  }

  // epilogue: C/D layout col=lane&15, row=(lane>>4)*4+reg
  const int row0 = by * BM2 + wr + (lane >> 4) * 4;
  const int col0 = bx * BN2 + wc + fm;

  if constexpr (EPI == 0) {
    // fused QKV: N=3072; segment uniform per block (256-col blocks, 1024-col segments)
    const int seg = bx >> 2;  // 0=Q, 1=K, 2=V
    const float* bias = (seg == 0) ? b0 : (seg == 1) ? b1 : b2;
#pragma unroll
    for (int i = 0; i < 8; ++i) {
#pragma unroll
      for (int j = 0; j < 4; ++j) {
        const int n = col0 + j * 16;
        const int nl = n & 1023;
        const float bv = bias[nl];
#pragma unroll
        for (int r = 0; r < 4; ++r) {
          const int m = row0 + i * 16 + r;
          float v = acc[i][j][r] + bv;
          if (seg < 2) {
            bf16_t* C = (bf16_t*)(seg == 0 ? C0 : C1);
            C[(size_t)m * D_DIM + nl] = (bf16_t)v;
          } else {
            // Vt[b][n][s]: b = m>>12, s = m&4095
            bf16_t* C = (bf16_t*)C2;
            C[((size_t)(m >> 12) << 22) + (size_t)nl * S_DIM + (m & (S_DIM - 1))] = (bf16_t)v;
          }
        }
      }
    }
  } else {
#pragma unroll
    for (int i = 0; i < 8; ++i) {
#pragma unroll
      for (int j = 0; j < 4; ++j) {
        const int n = col0 + j * 16;
#pragma unroll
        for (int r = 0; r < 4; ++r) {
          const int m = row0 + i * 16 + r;
          float v = acc[i][j][r];
          if constexpr (EPI == 2) {
            bf16_t* C = (bf16_t*)C0 + (size_t)lz * sC;
            float s = 1.0f / (1.0f + __expf(-v * scale));
            C[(size_t)m * ldc + n] = (bf16_t)s;
          } else {
            float* C = (float*)C0 + (size_t)lz * sC;
            C[(size_t)m * ldc + n] = v;
          }
        }
      }
    }
  }
}

extern "C" void kernel_launch(void* const* d_in, const int* in_sizes, int n_in,
                              void* d_out, int out_size, void* d_ws, size_t ws_size,
                              hipStream_t stream) {
  const float* X  = (const float*)d_in[0];
  const float* Wq = (const float*)d_in[1];
  const float* bq = (const float*)d_in[2];
  const float* Wk = (const float*)d_in[3];
  const float* bk = (const float*)d_in[4];
  const float* Wv = (const float*)d_in[5];
  const float* bv = (const float*)d_in[6];
  float* out = (float*)d_out;

  const int M = B_DIM * S_DIM;                 // 16384
  const size_t SD = (size_t)S_DIM * D_DIM;     // 4M per-batch Q/K/V elements
  const size_t E  = (size_t)M * D_DIM;         // 16M
  const size_t PE1 = (size_t)S_DIM * S_DIM;    // 16M (one batch of P)
  const size_t WE = (size_t)D_DIM * D_DIM;

  size_t need4 = (4 * PE1 + 3 * E + 3 * WE) * sizeof(bf16_t);
  const int PB = (ws_size >= need4) ? 4 : 1;
  const size_t psz = (size_t)PB * PE1;

  bf16_t* ws = (bf16_t*)d_ws;
  bf16_t* P   = ws;      // P region
  bf16_t* Xb  = ws;      // aliases P: Xb dead before first P write (same-stream ordering)
  bf16_t* Qb  = ws + psz;
  bf16_t* Kb  = Qb + E;
  bf16_t* Vt  = Kb + E;  // [B][D][S]
  bf16_t* Wt  = Vt + E;  // [3072][1024] concat of Wq^T, Wk^T, Wv^T

  // 1. cast X to bf16
  cast_f32_bf16<<<dim3((unsigned)(E / 8 / 256)), dim3(256), 0, stream>>>(X, Xb);

  // 2. transpose+cast weights into concatenated Wt
  dim3 tg(D_DIM / 32, D_DIM / 32), tb(32, 8);
  transpose_cast_1024<<<tg, tb, 0, stream>>>(Wq, Wt);
  transpose_cast_1024<<<tg, tb, 0, stream>>>(Wk, Wt + WE);
  transpose_cast_1024<<<tg, tb, 0, stream>>>(Wv, Wt + 2 * WE);

  // 3. fused QKV projection: [16384,1024] x [3072,1024]^T, 256^2 tiles
  dim3 pg(3 * D_DIM / BN2, M / BM2, 1);  // (12, 64) -> 768 blocks, %8==0
  gemm256<0, false><<<pg, dim3(512), 0, stream>>>(
      Xb, Wt, Qb, Kb, Vt, bq, bk, bv, D_DIM, D_DIM, D_DIM, D_DIM, 1.0f, 0, 0, 0);

  // 4/5. scores (sigmoid fused) then PV, PB batches at a time
  const float scale = 0.03125f;  // 1/sqrt(1024)
  for (int b0 = 0; b0 < B_DIM; b0 += PB) {
    dim3 sg(S_DIM / BN2, S_DIM / BM2, PB);  // (16, 16, PB) -> %8==0
    gemm256<2, false><<<sg, dim3(512), 0, stream>>>(
        Qb + (size_t)b0 * SD, Kb + (size_t)b0 * SD, P,
        nullptr, nullptr, nullptr, nullptr, nullptr,
        D_DIM, D_DIM, D_DIM, S_DIM, scale, SD, SD, PE1);
    // PV with swapped grid: x = row-blocks so consecutive blocks share a Vt panel
    dim3 vg(S_DIM / BM2, D_DIM / BN2, PB);  // (16, 4, PB) -> %8==0
    gemm256<3, true><<<vg, dim3(512), 0, stream>>>(
        P, Vt + (size_t)b0 * SD, out + (size_t)b0 * SD,
        nullptr, nullptr, nullptr, nullptr, nullptr,
        S_DIM, S_DIM, S_DIM, D_DIM, 1.0f, PE1, SD, SD);
  }
}

// Round 4
// 535.627 us; speedup vs baseline: 1.0413x; 1.0413x over previous
//
#include <hip/hip_runtime.h>
#include <hip/hip_bf16.h>

typedef __bf16 bf16_t;
typedef bf16_t bf16x8 __attribute__((ext_vector_type(8)));
typedef float f32x4 __attribute__((ext_vector_type(4)));

constexpr int D_DIM = 1024;
constexpr int S_DIM = 4096;
constexpr int B_DIM = 4;

// ---------------- elementwise cast X: fp32 -> bf16 ----------------
__global__ void cast_f32_bf16(const float* __restrict__ in, bf16_t* __restrict__ out) {
  size_t i = ((size_t)blockIdx.x * blockDim.x + threadIdx.x) * 8;
  float4 a = *(const float4*)(in + i);
  float4 b = *(const float4*)(in + i + 4);
  bf16x8 o;
  o[0] = (bf16_t)a.x; o[1] = (bf16_t)a.y; o[2] = (bf16_t)a.z; o[3] = (bf16_t)a.w;
  o[4] = (bf16_t)b.x; o[5] = (bf16_t)b.y; o[6] = (bf16_t)b.z; o[7] = (bf16_t)b.w;
  *(bf16x8*)(out + i) = o;
}

// ---------------- transpose + cast weight: [1024][1024] f32 -> bf16 transposed ----
__global__ void transpose_cast_1024(const float* __restrict__ in, bf16_t* __restrict__ out) {
  __shared__ float t[32][33];
  int x0 = blockIdx.x * 32, y0 = blockIdx.y * 32;
#pragma unroll
  for (int i = 0; i < 32; i += 8)
    t[threadIdx.y + i][threadIdx.x] =
        in[(size_t)(y0 + threadIdx.y + i) * D_DIM + (x0 + threadIdx.x)];
  __syncthreads();
#pragma unroll
  for (int i = 0; i < 32; i += 8)
    out[(size_t)(x0 + threadIdx.y + i) * D_DIM + (y0 + threadIdx.x)] =
        (bf16_t)t[threadIdx.x][threadIdx.y + i];
}

// ================= 256x256 8-phase GEMM (m201 template, faithful port) =================
// BM=BN=256, BK=64 per K-tile, 512 threads = 8 waves (2M x 4N), per-wave out 128x64.
// LDS 128 KiB STATIC: buf0{A,B} + buf1{A,B}, each tile 256x64 bf16 = 32 KB.
// Swizzle: physical 16B-granule g of row r holds logical granule g^(r&7)
// (applied on global SOURCE addr for global_load_lds + on ds_read addr; rule #21).
// Per-phase ds_reads 12/8/4/8; stages 1/1/0/1/2/1/0/2; vmcnt(2)@ph4, vmcnt(4)@ph8.
constexpr int BM2 = 256, BN2 = 256;

#define VMCNT4 asm volatile("s_waitcnt vmcnt(4)" ::: "memory")
#define VMCNT2 asm volatile("s_waitcnt vmcnt(2)" ::: "memory")
#define VMCNT0 asm volatile("s_waitcnt vmcnt(0)" ::: "memory")
#define LGKM8  asm volatile("s_waitcnt lgkmcnt(8)" ::: "memory")
#define LGKM0  asm volatile("s_waitcnt lgkmcnt(0)" ::: "memory")
#define SCHEDB __builtin_amdgcn_sched_barrier(0)
#define CFENCE asm volatile("" ::: "memory")
#define BAR __builtin_amdgcn_s_barrier()
#define PRIO1 __builtin_amdgcn_s_setprio(1)
#define PRIO0 __builtin_amdgcn_s_setprio(0)

// stage one 128-row x 64-col bf16 half-tile into LDS (2 x global_load_lds, 16B/lane).
// LDS dest is linear (wave-uniform base + lane*16); source granule pre-swizzled.
__device__ __forceinline__ void stage_half(const bf16_t* __restrict__ g, int ld,
                                           char* lds, int tid) {
  const int w = tid >> 6, l = tid & 63;
  const int rw = l >> 3;          // row within this wave's 8-row group (== row&7)
  const int gl = (l & 7) ^ rw;    // swizzled source 16B-granule
  char* l0 = lds + w * 1024;      // wave-uniform
  const bf16_t* s0 = g + (size_t)(w * 8 + rw) * ld + gl * 8;
  __builtin_amdgcn_global_load_lds((const __attribute__((address_space(1))) void*)s0,
                                   (__attribute__((address_space(3))) void*)l0, 16, 0, 0);
  __builtin_amdgcn_global_load_lds(
      (const __attribute__((address_space(1))) void*)(s0 + (size_t)64 * ld),
      (__attribute__((address_space(3))) void*)(l0 + 8192), 16, 0, 0);
}

// load 4 A-frags (M-set s: rows wr + s*64 .. +63) x 2 K-halves, swizzled ds_read_b128
__device__ __forceinline__ void load_a4(const char* __restrict__ At, int wr, int fm, int s,
                                        int kxa, int kxb, bf16x8 (&af)[4][2]) {
#pragma unroll
  for (int m = 0; m < 4; ++m) {
    const char* p = At + (wr + (s * 4 + m) * 16 + fm) * 128;
    af[m][0] = *(const bf16x8*)(p + kxa);
    af[m][1] = *(const bf16x8*)(p + kxb);
  }
}

// load 2 B-frags (bfr[n0], bfr[n0+1]) x 2 K-halves
__device__ __forceinline__ void load_b2(const char* __restrict__ Bt_, int wc, int fm, int n0,
                                        int kxa, int kxb, bf16x8 (&bfr)[4][2]) {
#pragma unroll
  for (int n = n0; n < n0 + 2; ++n) {
    const char* p = Bt_ + (wc + n * 16 + fm) * 128;
    bfr[n][0] = *(const bf16x8*)(p + kxa);
    bfr[n][1] = *(const bf16x8*)(p + kxb);
  }
}

// one C-quadrant (4M x 2N frags) x K=64 -> 16 MFMA (kh-outer: dependent pairs separated)
__device__ __forceinline__ void mfma_q(f32x4 (&acc)[8][4], const bf16x8 (&af)[4][2],
                                       const bf16x8 (&bfr)[4][2], int ms, int ns) {
#pragma unroll
  for (int kh = 0; kh < 2; ++kh)
#pragma unroll
    for (int m = 0; m < 4; ++m)
#pragma unroll
      for (int n = 0; n < 2; ++n)
        acc[ms * 4 + m][ns * 2 + n] = __builtin_amdgcn_mfma_f32_16x16x32_bf16(
            af[m][kh], bfr[ns * 2 + n][kh], acc[ms * 4 + m][ns * 2 + n], 0, 0, 0);
}

// EPI: 0 = fused QKV projection (Q,K row-major + bias; V transposed + bias)
//      2 = bf16 out, sigmoid(v*scale)   (scores -> P)
//      3 = fp32 out                      (PV -> out)
template <int EPI, bool SWAP>
__global__ __launch_bounds__(512, 2) void gemm256(
    const bf16_t* __restrict__ A, const bf16_t* __restrict__ Bt,
    void* __restrict__ C0, void* __restrict__ C1, void* __restrict__ C2,
    const float* __restrict__ b0, const float* __restrict__ b1, const float* __restrict__ b2,
    int K, int lda, int ldb, int ldc, float scale,
    size_t sA, size_t sB, size_t sC) {
  __shared__ __align__(16) char smem[131072];
  char* const A0t = smem;            // buf0 A tile (even K-tiles)
  char* const B0t = smem + 32768;    // buf0 B tile
  char* const A1t = smem + 65536;    // buf1 A tile (odd K-tiles)
  char* const B1t = smem + 98304;    // buf1 B tile

  const int tid = threadIdx.x;
  const int lane = tid & 63;
  const int w = tid >> 6;
  const int wr = (w >> 2) * 128;     // wave row base (2 M-waves)
  const int wc = (w & 3) * 64;       // wave col base (4 N-waves)
  const int fm = lane & 15;
  const int ssw = (fm & 7) << 4;             // row-dependent swizzle term
  const int kp = (lane >> 4) << 4;           // 0,16,32,48
  const int kxa = kp ^ ssw;                  // physical within-row byte, K-half 0
  const int kxb = (64 | kp) ^ ssw;           // K-half 1

  // ---- T1: bijective XCD-aware block remap (all grids have nwg % 8 == 0).
  const int nx = gridDim.x, ny = gridDim.y;
  const int nwg = nx * ny * gridDim.z;
  const int flat = blockIdx.x + nx * (blockIdx.y + ny * blockIdx.z);
  const int q = nwg >> 3;
  const int L = (flat & 7) * q + (flat >> 3);
  const int lx = L % nx;
  const int lt = L / nx;
  const int ly = lt % ny;
  const int lz = lt / ny;

  const int bx = SWAP ? ly : lx;
  const int by = SWAP ? lx : ly;

  const bf16_t* Ag = A + (size_t)lz * sA + (size_t)by * BM2 * lda;
  const bf16_t* Bg = Bt + (size_t)lz * sB + (size_t)bx * BN2 * ldb;

  f32x4 acc[8][4] = {};
  bf16x8 af[4][2], bfr[4][2];

  const int NI = K / 128;  // iterations; each covers 2 K-tiles of 64

  // prologue: stage tile0 A+B (buf0) and tile1 B (buf1) = 12 loads.
  // tile1 A is staged during ph1/ph2.
  stage_half(Ag, lda, A0t, tid);
  stage_half(Ag + (size_t)128 * lda, lda, A0t + 16384, tid);
  stage_half(Bg, ldb, B0t, tid);
  stage_half(Bg + (size_t)128 * ldb, ldb, B0t + 16384, tid);
  stage_half(Bg + 64, ldb, B1t, tid);
  stage_half(Bg + 64 + (size_t)128 * ldb, ldb, B1t + 16384, tid);
  VMCNT4;  // drain tile0 (8 oldest); tile1-B (4) stays in flight
  BAR;

  for (int it = 0; it < NI; ++it) {
    const bool last = (it == NI - 1);
    const bf16_t* Ao  = Ag + (size_t)(2 * it + 1) * 64;  // odd tile A (buf1)
    const bf16_t* Ae2 = Ag + (size_t)(2 * it + 2) * 64;  // tile t+2 (buf0)
    const bf16_t* Be2 = Bg + (size_t)(2 * it + 2) * 64;
    const bf16_t* Bo2 = Bg + (size_t)(2 * it + 3) * 64;  // tile t+3 B (buf1)

    // ph1: 12 ds_reads (af s0 + bfr[0..1]); stage A-odd h0
    load_a4(A0t, wr, fm, 0, kxa, kxb, af);
    load_b2(B0t, wc, fm, 0, kxa, kxb, bfr);
    stage_half(Ao, lda, A1t, tid);
    LGKM8; CFENCE; BAR;
    LGKM0; SCHEDB;
    PRIO1; mfma_q(acc, af, bfr, 0, 0); PRIO0;
    BAR;

    // ph2: 8 ds_reads (af s1); stage A-odd h1
    load_a4(A0t, wr, fm, 1, kxa, kxb, af);
    stage_half(Ao + (size_t)128 * lda, lda, A1t + 16384, tid);
    CFENCE; BAR;
    LGKM0; SCHEDB;
    PRIO1; mfma_q(acc, af, bfr, 1, 0); PRIO0;
    BAR;

    // ph3: 4 ds_reads (bfr[2..3]); no stage (B0 frees only after this phase)
    load_b2(B0t, wc, fm, 2, kxa, kxb, bfr);
    CFENCE; BAR;
    LGKM0; SCHEDB;
    PRIO1; mfma_q(acc, af, bfr, 1, 1); PRIO0;
    BAR;

    // ph4: 8 ds_reads (af s0 reload); stage B(t+2) h0 -> B0 (B0 reads done ph3);
    //      vmcnt(2): drain A-odd (+any older), keep B(t+2)h0 in flight
    load_a4(A0t, wr, fm, 0, kxa, kxb, af);
    if (!last) stage_half(Be2, ldb, B0t, tid);
    CFENCE; BAR;
    LGKM0; SCHEDB;
    PRIO1; mfma_q(acc, af, bfr, 0, 1); PRIO0;
    if (last) { VMCNT0; } else { VMCNT2; }
    BAR;

    // ph5: 12 ds_reads (af-odd s0 + bfr-odd[0..1]); stage B(t+2) h1 + A(t+2) h0 -> buf0
    load_a4(A1t, wr, fm, 0, kxa, kxb, af);
    load_b2(B1t, wc, fm, 0, kxa, kxb, bfr);
    if (!last) {
      stage_half(Be2 + (size_t)128 * ldb, ldb, B0t + 16384, tid);
      stage_half(Ae2, lda, A0t, tid);
    }
    LGKM8; CFENCE; BAR;
    LGKM0; SCHEDB;
    PRIO1; mfma_q(acc, af, bfr, 0, 0); PRIO0;
    BAR;

    // ph6: 8 ds_reads (af-odd s1); stage A(t+2) h1
    load_a4(A1t, wr, fm, 1, kxa, kxb, af);
    if (!last) stage_half(Ae2 + (size_t)128 * lda, lda, A0t + 16384, tid);
    CFENCE; BAR;
    LGKM0; SCHEDB;
    PRIO1; mfma_q(acc, af, bfr, 1, 0); PRIO0;
    BAR;

    // ph7: 4 ds_reads (bfr-odd[2..3]); no stage (B1 frees only after this phase)
    load_b2(B1t, wc, fm, 2, kxa, kxb, bfr);
    CFENCE; BAR;
    LGKM0; SCHEDB;
    PRIO1; mfma_q(acc, af, bfr, 1, 1); PRIO0;
    BAR;

    // ph8: 8 ds_reads (af-odd s0 reload); stage B(t+3) h0+h1 -> B1 (B1 reads done ph7);
    //      vmcnt(4): drain tile t+2 (A+B), keep B(t+3) in flight
    load_a4(A1t, wr, fm, 0, kxa, kxb, af);
    if (!last) {
      stage_half(Bo2, ldb, B1t, tid);
      stage_half(Bo2 + (size_t)128 * ldb, ldb, B1t + 16384, tid);
    }
    CFENCE; BAR;
    LGKM0; SCHEDB;
    PRIO1; mfma_q(acc, af, bfr, 0, 1); PRIO0;
    if (!last) { VMCNT4; }
    BAR;
  }

  // epilogue: C/D layout col=lane&15, row=(lane>>4)*4+reg
  const int row0 = by * BM2 + wr + (lane >> 4) * 4;
  const int col0 = bx * BN2 + wc + fm;

  if constexpr (EPI == 0) {
    // fused QKV: N=3072; segment uniform per block (256-col blocks, 1024-col segments)
    const int seg = bx >> 2;  // 0=Q, 1=K, 2=V
    const float* bias = (seg == 0) ? b0 : (seg == 1) ? b1 : b2;
#pragma unroll
    for (int i = 0; i < 8; ++i) {
#pragma unroll
      for (int j = 0; j < 4; ++j) {
        const int n = col0 + j * 16;
        const int nl = n & 1023;
        const float bv = bias[nl];
#pragma unroll
        for (int r = 0; r < 4; ++r) {
          const int m = row0 + i * 16 + r;
          float v = acc[i][j][r] + bv;
          if (seg < 2) {
            bf16_t* C = (bf16_t*)(seg == 0 ? C0 : C1);
            C[(size_t)m * D_DIM + nl] = (bf16_t)v;
          } else {
            // Vt[b][n][s]: b = m>>12, s = m&4095
            bf16_t* C = (bf16_t*)C2;
            C[((size_t)(m >> 12) << 22) + (size_t)nl * S_DIM + (m & (S_DIM - 1))] = (bf16_t)v;
          }
        }
      }
    }
  } else {
#pragma unroll
    for (int i = 0; i < 8; ++i) {
#pragma unroll
      for (int j = 0; j < 4; ++j) {
        const int n = col0 + j * 16;
#pragma unroll
        for (int r = 0; r < 4; ++r) {
          const int m = row0 + i * 16 + r;
          float v = acc[i][j][r];
          if constexpr (EPI == 2) {
            bf16_t* C = (bf16_t*)C0 + (size_t)lz * sC;
            float s = 1.0f / (1.0f + __expf(-v * scale));
            C[(size_t)m * ldc + n] = (bf16_t)s;
          } else {
            float* C = (float*)C0 + (size_t)lz * sC;
            C[(size_t)m * ldc + n] = v;
          }
        }
      }
    }
  }
}

extern "C" void kernel_launch(void* const* d_in, const int* in_sizes, int n_in,
                              void* d_out, int out_size, void* d_ws, size_t ws_size,
                              hipStream_t stream) {
  const float* X  = (const float*)d_in[0];
  const float* Wq = (const float*)d_in[1];
  const float* bq = (const float*)d_in[2];
  const float* Wk = (const float*)d_in[3];
  const float* bk = (const float*)d_in[4];
  const float* Wv = (const float*)d_in[5];
  const float* bv = (const float*)d_in[6];
  float* out = (float*)d_out;

  const int M = B_DIM * S_DIM;                 // 16384
  const size_t SD = (size_t)S_DIM * D_DIM;     // 4M per-batch Q/K/V elements
  const size_t E  = (size_t)M * D_DIM;         // 16M
  const size_t PE1 = (size_t)S_DIM * S_DIM;    // 16M (one batch of P)
  const size_t WE = (size_t)D_DIM * D_DIM;

  size_t need4 = (4 * PE1 + 3 * E + 3 * WE) * sizeof(bf16_t);
  const int PB = (ws_size >= need4) ? 4 : 1;
  const size_t psz = (size_t)PB * PE1;

  bf16_t* ws = (bf16_t*)d_ws;
  bf16_t* P   = ws;      // P region
  bf16_t* Xb  = ws;      // aliases P: Xb dead before first P write (same-stream ordering)
  bf16_t* Qb  = ws + psz;
  bf16_t* Kb  = Qb + E;
  bf16_t* Vt  = Kb + E;  // [B][D][S]
  bf16_t* Wt  = Vt + E;  // [3072][1024] concat of Wq^T, Wk^T, Wv^T

  // 1. cast X to bf16
  cast_f32_bf16<<<dim3((unsigned)(E / 8 / 256)), dim3(256), 0, stream>>>(X, Xb);

  // 2. transpose+cast weights into concatenated Wt
  dim3 tg(D_DIM / 32, D_DIM / 32), tb(32, 8);
  transpose_cast_1024<<<tg, tb, 0, stream>>>(Wq, Wt);
  transpose_cast_1024<<<tg, tb, 0, stream>>>(Wk, Wt + WE);
  transpose_cast_1024<<<tg, tb, 0, stream>>>(Wv, Wt + 2 * WE);

  // 3. fused QKV projection: [16384,1024] x [3072,1024]^T, 256^2 tiles
  dim3 pg(3 * D_DIM / BN2, M / BM2, 1);  // (12, 64) -> 768 blocks, %8==0
  gemm256<0, false><<<pg, dim3(512), 0, stream>>>(
      Xb, Wt, Qb, Kb, Vt, bq, bk, bv, D_DIM, D_DIM, D_DIM, D_DIM, 1.0f, 0, 0, 0);

  // 4/5. scores (sigmoid fused) then PV, PB batches at a time
  const float scale = 0.03125f;  // 1/sqrt(1024)
  for (int b0 = 0; b0 < B_DIM; b0 += PB) {
    dim3 sg(S_DIM / BN2, S_DIM / BM2, PB);  // (16, 16, PB) -> %8==0
    gemm256<2, false><<<sg, dim3(512), 0, stream>>>(
        Qb + (size_t)b0 * SD, Kb + (size_t)b0 * SD, P,
        nullptr, nullptr, nullptr, nullptr, nullptr,
        D_DIM, D_DIM, D_DIM, S_DIM, scale, SD, SD, PE1);
    // PV with swapped grid: x = row-blocks so consecutive blocks share a Vt panel
    dim3 vg(S_DIM / BM2, D_DIM / BN2, PB);  // (16, 4, PB) -> %8==0
    gemm256<3, true><<<vg, dim3(512), 0, stream>>>(
        P, Vt + (size_t)b0 * SD, out + (size_t)b0 * SD,
        nullptr, nullptr, nullptr, nullptr, nullptr,
        S_DIM, S_DIM, S_DIM, D_DIM, 1.0f, PE1, SD, SD);
  }
}